// Round 8
// baseline (318.497 us; speedup 1.0000x reference)
//
#include <hip/hip_runtime.h>
#include <hip/hip_fp16.h>

typedef float f32x4 __attribute__((ext_vector_type(4)));
typedef __bf16 bf16x8 __attribute__((ext_vector_type(8)));

#define BB_ 8
#define TT_ 4096
#define DD_ 1024
#define MM_ (BB_*TT_)   // 32768
#define KK_ DD_         // 1024

#define NCH 64
#define LCH (TT_/NCH)   // 64

static __device__ __forceinline__ unsigned short f2bf_rn(float f) {
  unsigned int u = __float_as_uint(f);
  u += 0x7FFFu + ((u >> 16) & 1u);
  return (unsigned short)(u >> 16);
}

// ---------------- conversion: f32 -> bf16 bits (vectorized) ----------------
__global__ void cvt_f32_bf16(const float4* __restrict__ src,
                             ushort4* __restrict__ dst, int n4) {
  int stride = gridDim.x * blockDim.x;
  for (int i = blockIdx.x * blockDim.x + threadIdx.x; i < n4; i += stride) {
    float4 v = src[i];
    ushort4 o;
    o.x = f2bf_rn(v.x); o.y = f2bf_rn(v.y);
    o.z = f2bf_rn(v.z); o.w = f2bf_rn(v.w);
    dst[i] = o;
  }
}

// W interleave: Wcat row = (D>>7)*256 + (isH?128:0) + (D&127), D = out channel
__global__ void cvt_w(const float4* __restrict__ Wz4,
                      const float4* __restrict__ Wh4,
                      ushort4* __restrict__ Wcat) {
  int flat = blockIdx.x * 256 + threadIdx.x;     // 0..524287
  int mtx = flat >> 18;                          // 0 = Wz, 1 = Wh
  int j = flat & 262143;
  float4 v = (mtx ? Wh4 : Wz4)[j];
  int D = j >> 8;                                // source row 0..1023
  int kq = j & 255;                              // float4 col
  int row = ((D >> 7) << 8) + (mtx << 7) + (D & 127);
  ushort4 o;
  o.x = f2bf_rn(v.x); o.y = f2bf_rn(v.y);
  o.z = f2bf_rn(v.z); o.w = f2bf_rn(v.w);
  Wcat[(size_t)row * 256 + kq] = o;
}

// ---------------- GEMM: 256^2 tile, BK=64, R4 4-phase K-loop --------------
__device__ __forceinline__ void gload_lds16(const void* g, void* l) {
  __builtin_amdgcn_global_load_lds(
      (const __attribute__((address_space(1))) void*)g,
      (__attribute__((address_space(3))) void*)l, 16, 0, 0);
}

#define STA(q, nb_, kkh) gload_lds16(pXa + (q) * 65536 + (kkh), (nb_) + (q) * 8192 + wofs)
#define STB(q, nb_, kkh) gload_lds16(pWb + (q) * 65536 + (kkh), (nb_) + 32768 + (q) * 8192 + wofs)

#define PHASE(cb_, mh, kh, STAGEOPS, WAITOPS) do {                          \
    const char* Ab_ = (cb_);                                                \
    const char* Bb_ = (cb_) + 32768;                                        \
    const int sk_ = (kh) ? sk1 : sk0;                                       \
    bf16x8 af_[4];                                                          \
    _Pragma("unroll")                                                       \
    for (int ii = 0; ii < 4; ++ii)                                          \
      af_[ii] = *reinterpret_cast<const bf16x8*>(                           \
          Ab_ + rA7 + (mh) * 8192 + ii * 2048 + sk_);                       \
    if ((mh) == 0) {                                                        \
      _Pragma("unroll")                                                     \
      for (int j = 0; j < 4; ++j)                                           \
        bfv[j] = *reinterpret_cast<const bf16x8*>(                          \
            Bb_ + rB7 + j * 2048 + sk_);                                    \
    }                                                                       \
    STAGEOPS;                                                               \
    WAITOPS;                                                                \
    __builtin_amdgcn_s_barrier();                                           \
    asm volatile("s_waitcnt lgkmcnt(0)" ::: "memory");                      \
    __builtin_amdgcn_sched_barrier(0);                                      \
    __builtin_amdgcn_s_setprio(1);                                          \
    _Pragma("unroll")                                                       \
    for (int ii = 0; ii < 4; ++ii)                                          \
      _Pragma("unroll")                                                     \
      for (int j = 0; j < 4; ++j)                                           \
        acc[(mh) * 4 + ii][j] = __builtin_amdgcn_mfma_f32_16x16x32_bf16(    \
            af_[ii], bfv[j], acc[(mh) * 4 + ii][j], 0, 0, 0);               \
    __builtin_amdgcn_s_setprio(0);                                          \
    asm volatile("" ::: "memory");                                          \
    __builtin_amdgcn_s_barrier();                                           \
  } while (0)

__global__ __launch_bounds__(512, 2) void gemm_fused(
    const unsigned short* __restrict__ Xb,   // [M][K] bf16 bits
    const unsigned short* __restrict__ Wb,   // [2048][K] bf16 bits (Wcat)
    const float* __restrict__ bz, const float* __restrict__ bh,
    __half* __restrict__ Zb, __half* __restrict__ Gb,   // each [M][1024]
    float* __restrict__ Pp, float* __restrict__ Qq)     // [B][64][1024]
{
  extern __shared__ __align__(16) char smem[];   // 2 x (A 32KB + B 32KB)
  const int tid  = threadIdx.x;
  const int wave = tid >> 6;
  const int lane = tid & 63;
  const int wm = wave >> 2, wn = wave & 3;       // 2M x 4N waves
  const int fr = lane & 15, kg = lane >> 4;

  // XCD-bijective swizzle (1024 % 8 == 0); N-fastest within each XCD strip.
  int swz = (blockIdx.x & 7) * 128 + (blockIdx.x >> 3);
  const int m0 = (swz >> 3) * 256;
  const int e0 = (swz & 7) * 256;   // Wcat row tile
  const int dg = swz & 7;           // channel group (d base = dg*128)

  // staging per-thread constants (pre-swizzled global source)
  const int arow = tid >> 3;                         // 0..63 row within round
  const int aslx = ((tid & 7) ^ (arow & 7)) * 8;     // swizzled 16B-chunk, halfs
  const unsigned short* pXa = Xb + (size_t)(m0 + arow) * KK_ + aslx;
  const unsigned short* pWb = Wb + (size_t)(e0 + arow) * KK_ + aslx;
  const int wofs = wave * 1024;                      // wave slice of round (bytes)

  // ds_read per-thread constants (swizzled read side)
  const int rA7 = (wm * 128 + fr) * 128;             // A row byte offset
  const int rB7 = (wn * 64 + fr) * 128;              // B row byte offset
  const int fx = fr & 7;
  const int sk0 = (kg ^ fx) * 16;                    // k-half 0 slot byte
  const int sk1 = sk0 ^ 64;                          // k-half 1 slot byte

  f32x4 acc[8][4];
  #pragma unroll
  for (int i = 0; i < 8; i++)
    #pragma unroll
    for (int j = 0; j < 4; j++)
      acc[i][j] = (f32x4){0.f, 0.f, 0.f, 0.f};
  bf16x8 bfv[4];

  // prologue: stage K-tile 0 into buf0
  STA(0, smem, 0); STA(2, smem, 0); STB(0, smem, 0);
  STB(1, smem, 0); STB(2, smem, 0); STB(3, smem, 0);
  STA(1, smem, 0); STA(3, smem, 0);
  asm volatile("s_waitcnt vmcnt(2)" ::: "memory");
  __builtin_amdgcn_s_barrier();

  #pragma unroll 1
  for (int t = 0; t < 15; ++t) {                     // tiles 0..14, prefetch t+1
    char* cb = smem + ((t & 1) << 16);
    char* nb = smem + (((t + 1) & 1) << 16);
    const int kn = (t + 1) * 64;
    PHASE(cb, 0, 0, {STA(0, nb, kn); STA(2, nb, kn); STB(0, nb, kn);},
          asm volatile("s_waitcnt vmcnt(3)" ::: "memory"));
    PHASE(cb, 1, 0, {STB(1, nb, kn); STB(2, nb, kn); STB(3, nb, kn);}, );
    PHASE(cb, 0, 1, {STA(1, nb, kn); STA(3, nb, kn);}, );
    PHASE(cb, 1, 1, {},
          asm volatile("s_waitcnt vmcnt(2)" ::: "memory"));
  }
  {                                                  // peeled tile 15 (buf1)
    char* cb = smem + 65536;
    PHASE(cb, 0, 0, {}, asm volatile("s_waitcnt vmcnt(0)" ::: "memory"));
    PHASE(cb, 1, 0, {}, );
    PHASE(cb, 0, 1, {}, );
    PHASE(cb, 1, 1, {}, );
  }
  // last PHASE's trailing barrier: all LDS reads done -> smem reusable

  // ===== epilogue E1: activation, write (z,g) into swizzled LDS tile ======
  // sc: [256 t][16 slots][4 d-lane][2 (z,g)] halfs, slot = (d>>2) ^ (t&15)
  __half* sc = (__half*)smem;                        // 131072 B exactly
  const bool isZ = (wn < 2);
  const int dloc0 = (wn & 1) * 64;
  const int zg = isZ ? 0 : 1;
  const float* bias = isZ ? bz : bh;
  float bvv[4];
  #pragma unroll
  for (int j = 0; j < 4; ++j) bvv[j] = bias[dg * 128 + dloc0 + j * 16 + fr];

  #pragma unroll
  for (int a = 0; a < 8; ++a) {
    const int tl = wm * 128 + (a >> 2) * 64 + (a & 3) * 16 + kg * 4;
    #pragma unroll
    for (int j = 0; j < 4; ++j) {
      const int d = dloc0 + j * 16 + fr;
      #pragma unroll
      for (int r = 0; r < 4; ++r) {
        float val = acc[a][j][r] + bvv[j];
        float res;
        if (isZ) {
          res = 1.0f / (1.0f + __expf(-val));        // z = sigmoid(k)
        } else {
          res = (val >= 0.0f) ? (val + 0.5f)         // g(th)
                              : (1.0f / (1.0f + __expf(-val)));
        }
        const int t = tl + r;
        sc[t * 256 + ((d >> 2) ^ (t & 15)) * 8 + (d & 3) * 2 + zg] =
            __float2half(res);
      }
    }
  }
  __syncthreads();                                   // sc tile published

  // ===== epilogue E2: per-(64t chunk, channel) scan -> P,Q ================
  {
    const int dl = tid & 127, cgl = tid >> 7;        // channel, local chunk
    const int dq = dl >> 2, dlo = (dl & 3) * 2;
    float pp = 1.f, qq = 0.f;
    #pragma unroll 4
    for (int i = 0; i < 64; ++i) {
      const int t = cgl * 64 + i;
      unsigned int zw = *reinterpret_cast<const unsigned int*>(
          &sc[t * 256 + ((dq ^ (t & 15)) * 8) + dlo]);
      float z = __half2float(__ushort_as_half((unsigned short)(zw & 0xffff)));
      float g = __half2float(__ushort_as_half((unsigned short)(zw >> 16)));
      float aa = 1.f - z;
      pp *= aa;
      qq = fmaf(aa, qq, z * g);
    }
    const int b = m0 >> 12;
    const int cg = ((m0 & 4095) >> 6) + cgl;
    size_t po = ((size_t)b * NCH + cg) * DD_ + dg * 128 + dl;
    Pp[po] = pp;
    Qq[po] = qq;
  }

  // ===== epilogue E3: pack z/g from sc, coalesced global stores ===========
  {
    const int row = tid >> 1, hd = tid & 1;          // t-row, d-half (64 ch)
    const size_t rg = (size_t)m0 + row;
    __half* zdst = Zb + rg * DD_ + dg * 128 + hd * 64;
    __half* gdst = Gb + rg * DD_ + dg * 128 + hd * 64;
    const int t = row;
    #pragma unroll
    for (int k = 0; k < 8; ++k) {
      const int dq0 = hd * 16 + k * 2;               // d>>2 for d0 = hd*64+k*8
      uint4 i0 = *reinterpret_cast<const uint4*>(
          &sc[t * 256 + ((dq0 ^ (t & 15)) * 8)]);
      uint4 i1 = *reinterpret_cast<const uint4*>(
          &sc[t * 256 + (((dq0 + 1) ^ (t & 15)) * 8)]);
      uint4 zv, gv;
      zv.x = (i0.x & 0xffffu) | (i0.y << 16);
      zv.y = (i0.z & 0xffffu) | (i0.w << 16);
      zv.z = (i1.x & 0xffffu) | (i1.y << 16);
      zv.w = (i1.z & 0xffffu) | (i1.w << 16);
      gv.x = (i0.x >> 16) | (i0.y & 0xffff0000u);
      gv.y = (i0.z >> 16) | (i0.w & 0xffff0000u);
      gv.z = (i1.x >> 16) | (i1.y & 0xffff0000u);
      gv.w = (i1.z >> 16) | (i1.w & 0xffff0000u);
      *reinterpret_cast<uint4*>(zdst + k * 8) = zv;
      *reinterpret_cast<uint4*>(gdst + k * 8) = gv;
    }
  }
}

// ---------------- scan phase B: exclusive scan over chunks ----------------
__global__ __launch_bounds__(256) void scan_combine(
    const float* __restrict__ P, const float* __restrict__ Q,
    float* __restrict__ H) {
  const int d = blockIdx.x * 256 + threadIdx.x;   // gridDim.x = 4 -> d 0..1023
  const int b = blockIdx.y;
  float h = 0.f;
  for (int c = 0; c < NCH; ++c) {
    size_t o = ((size_t)b * NCH + c) * DD_ + d;
    H[o] = h;
    h = fmaf(P[o], h, Q[o]);
  }
}

// ---------------- scan phase C: apply + write output ----------------
__global__ __launch_bounds__(256) void scan_apply(
    const ushort4* __restrict__ Z, const ushort4* __restrict__ G,
    const float4* __restrict__ H, float4* __restrict__ out) {
  const int d4 = threadIdx.x;
  const int c  = blockIdx.x;
  const int b  = blockIdx.y;
  float4 h = H[((size_t)b * NCH + c) * (DD_ / 4) + d4];
  size_t base = ((size_t)b * TT_ + (size_t)c * LCH) * (DD_ / 4) + d4;
  for (int t = 0; t < LCH; ++t) {
    ushort4 uz = Z[base + (size_t)t * (DD_ / 4)];
    ushort4 ug = G[base + (size_t)t * (DD_ / 4)];
    float z, g, a;
    z = __half2float(__ushort_as_half(uz.x)); g = __half2float(__ushort_as_half(ug.x));
    a = 1.f - z; h.x = fmaf(a, h.x, z * g);
    z = __half2float(__ushort_as_half(uz.y)); g = __half2float(__ushort_as_half(ug.y));
    a = 1.f - z; h.y = fmaf(a, h.y, z * g);
    z = __half2float(__ushort_as_half(uz.z)); g = __half2float(__ushort_as_half(ug.z));
    a = 1.f - z; h.z = fmaf(a, h.z, z * g);
    z = __half2float(__ushort_as_half(uz.w)); g = __half2float(__ushort_as_half(ug.w));
    a = 1.f - z; h.w = fmaf(a, h.w, z * g);
    out[base + (size_t)t * (DD_ / 4)] = h;
  }
}

extern "C" void kernel_launch(void* const* d_in, const int* in_sizes, int n_in,
                              void* d_out, int out_size, void* d_ws, size_t ws_size,
                              hipStream_t stream) {
  const float* X  = (const float*)d_in[0];  // [8,4096,1024]
  const float* Wz = (const float*)d_in[1];  // [1024,1024]
  const float* bz = (const float*)d_in[2];
  const float* Wh = (const float*)d_in[3];
  const float* bh = (const float*)d_in[4];
  float* out = (float*)d_out;

  const size_t szXb = (size_t)MM_ * DD_ * 2;      // 64 MiB  bf16 X
  const size_t szWb = (size_t)2 * DD_ * DD_ * 2;  //  4 MiB  bf16 Wcat
  const size_t szZ  = (size_t)MM_ * DD_ * 2;      // 64 MiB  fp16 each
  const size_t szPQ = (size_t)BB_ * NCH * DD_ * 4;//  2 MiB  each

  char* ws = (char*)d_ws;
  unsigned short *Xb, *Wb;
  __half *Zb, *Gb;
  const size_t needA = szXb + szWb + 2 * szZ + 3 * szPQ;
  if (ws_size >= needA) {
    Xb = (unsigned short*)ws;              ws += szXb;
    Wb = (unsigned short*)ws;              ws += szWb;
  } else {
    // fallback: stage X/W inside d_out (dead after GEMM), scan state in ws
    Xb = (unsigned short*)d_out;
    Wb = (unsigned short*)((char*)d_out + szXb);
  }
  Zb = (__half*)ws;  ws += szZ;
  Gb = (__half*)ws;  ws += szZ;
  float* P = (float*)ws;  ws += szPQ;
  float* Q = (float*)ws;  ws += szPQ;
  float* H = (float*)ws;

  // 1) convert inputs to bf16 (X straight; W interleaved into Wcat)
  cvt_f32_bf16<<<2048, 256, 0, stream>>>((const float4*)X, (ushort4*)Xb,
                                         (int)((size_t)MM_ * DD_ / 4));
  cvt_w<<<2048, 256, 0, stream>>>((const float4*)Wz, (const float4*)Wh,
                                  (ushort4*)Wb);
  // 2) fused GEMM -> z, g, P, Q  (M=32768, N=2048 concat, K=1024)
  gemm_fused<<<(MM_ / 256) * ((2 * DD_) / 256), 512, 131072, stream>>>(
      Xb, Wb, bz, bh, Zb, Gb, P, Q);

  // 3) chunk combine + apply
  scan_combine<<<dim3(4, BB_), 256, 0, stream>>>(P, Q, H);
  scan_apply<<<dim3(NCH, BB_), 256, 0, stream>>>((const ushort4*)Zb, (const ushort4*)Gb,
                                                 (const float4*)H, (float4*)out);
}

// Round 9
// 264.137 us; speedup vs baseline: 1.2058x; 1.2058x over previous
//
#include <hip/hip_runtime.h>
#include <hip/hip_fp16.h>

typedef float f32x4 __attribute__((ext_vector_type(4)));
typedef __bf16 bf16x8 __attribute__((ext_vector_type(8)));

#define BB_ 8
#define TT_ 4096
#define DD_ 1024
#define MM_ (BB_*TT_)   // 32768
#define KK_ DD_         // 1024

#define NCH 64
#define LCH (TT_/NCH)   // 64

static __device__ __forceinline__ unsigned short f2bf_rn(float f) {
  unsigned int u = __float_as_uint(f);
  u += 0x7FFFu + ((u >> 16) & 1u);
  return (unsigned short)(u >> 16);
}

// ---------------- conversion: f32 -> bf16 bits (vectorized) ----------------
__global__ void cvt_f32_bf16(const float4* __restrict__ src,
                             ushort4* __restrict__ dst, int n4) {
  int stride = gridDim.x * blockDim.x;
  for (int i = blockIdx.x * blockDim.x + threadIdx.x; i < n4; i += stride) {
    float4 v = src[i];
    ushort4 o;
    o.x = f2bf_rn(v.x); o.y = f2bf_rn(v.y);
    o.z = f2bf_rn(v.z); o.w = f2bf_rn(v.w);
    dst[i] = o;
  }
}

// W interleave: Wcat row e = (D>>5)*64 + mtx*32 + (D&31).  Within each
// 64-col tile: cols 0..31 = Wz rows for 32 channels, cols 32..63 = Wh same
// channels -> a wave's j and j+2 fragments give (k, th) for the SAME channel.
__global__ void cvt_w(const float4* __restrict__ Wz4,
                      const float4* __restrict__ Wh4,
                      ushort4* __restrict__ Wcat) {
  int flat = blockIdx.x * 256 + threadIdx.x;     // 0..524287
  int mtx = flat >> 18;                          // 0 = Wz, 1 = Wh
  int j = flat & 262143;
  float4 v = (mtx ? Wh4 : Wz4)[j];
  int D = j >> 8;                                // source row 0..1023
  int kq = j & 255;                              // float4 col
  int e = ((D >> 5) << 6) + (mtx << 5) + (D & 31);
  ushort4 o;
  o.x = f2bf_rn(v.x); o.y = f2bf_rn(v.y);
  o.z = f2bf_rn(v.z); o.w = f2bf_rn(v.w);
  Wcat[(size_t)e * 256 + kq] = o;
}

// ---------------- GEMM: 256^2 tile, BK=64, R4 4-phase K-loop --------------
__device__ __forceinline__ void gload_lds16(const void* g, void* l) {
  __builtin_amdgcn_global_load_lds(
      (const __attribute__((address_space(1))) void*)g,
      (__attribute__((address_space(3))) void*)l, 16, 0, 0);
}

#define STA(q, nb_, kkh) gload_lds16(pXa + (q) * 65536 + (kkh), (nb_) + (q) * 8192 + wofs)
#define STB(q, nb_, kkh) gload_lds16(pWb + (q) * 65536 + (kkh), (nb_) + 32768 + (q) * 8192 + wofs)

#define PHASE(cb_, mh, kh, STAGEOPS, WAITOPS) do {                          \
    const char* Ab_ = (cb_);                                                \
    const char* Bb_ = (cb_) + 32768;                                        \
    const int sk_ = (kh) ? sk1 : sk0;                                       \
    bf16x8 af_[4];                                                          \
    _Pragma("unroll")                                                       \
    for (int ii = 0; ii < 4; ++ii)                                          \
      af_[ii] = *reinterpret_cast<const bf16x8*>(                           \
          Ab_ + rA7 + (mh) * 8192 + ii * 2048 + sk_);                       \
    if ((mh) == 0) {                                                        \
      _Pragma("unroll")                                                     \
      for (int j = 0; j < 4; ++j)                                           \
        bfv[j] = *reinterpret_cast<const bf16x8*>(                          \
            Bb_ + rB7 + j * 2048 + sk_);                                    \
    }                                                                       \
    STAGEOPS;                                                               \
    WAITOPS;                                                                \
    __builtin_amdgcn_s_barrier();                                           \
    asm volatile("s_waitcnt lgkmcnt(0)" ::: "memory");                      \
    __builtin_amdgcn_sched_barrier(0);                                      \
    __builtin_amdgcn_s_setprio(1);                                          \
    _Pragma("unroll")                                                       \
    for (int ii = 0; ii < 4; ++ii)                                          \
      _Pragma("unroll")                                                     \
      for (int j = 0; j < 4; ++j)                                           \
        acc[(mh) * 4 + ii][j] = __builtin_amdgcn_mfma_f32_16x16x32_bf16(    \
            af_[ii], bfv[j], acc[(mh) * 4 + ii][j], 0, 0, 0);               \
    __builtin_amdgcn_s_setprio(0);                                          \
    asm volatile("" ::: "memory");                                          \
    __builtin_amdgcn_s_barrier();                                           \
  } while (0)

__global__ __launch_bounds__(512, 2) void gemm_fused(
    const unsigned short* __restrict__ Xb,   // [M][K] bf16 bits
    const unsigned short* __restrict__ Wb,   // [2048][K] bf16 bits (Wcat)
    const float* __restrict__ bz, const float* __restrict__ bh,
    unsigned int* __restrict__ ZG,           // [M][1024] packed (z | g<<16)
    float* __restrict__ Pp, float* __restrict__ Qq)   // [B][64][1024]
{
  extern __shared__ __align__(16) char smem[];   // 2 x (A 32KB + B 32KB)
  const int tid  = threadIdx.x;
  const int wave = tid >> 6;
  const int lane = tid & 63;
  const int wm = wave >> 2, wn = wave & 3;       // 2M x 4N waves
  const int fr = lane & 15, kg = lane >> 4;

  // XCD-bijective swizzle (1024 % 8 == 0); N-fastest within each XCD strip.
  int swz = (blockIdx.x & 7) * 128 + (blockIdx.x >> 3);
  const int m0 = (swz >> 3) * 256;
  const int e0 = (swz & 7) * 256;                // Wcat col-tile base

  // staging per-thread constants (pre-swizzled global source)
  const int arow = tid >> 3;                         // 0..63 row within round
  const int aslx = ((tid & 7) ^ (arow & 7)) * 8;     // swizzled 16B-chunk, halfs
  const unsigned short* pXa = Xb + (size_t)(m0 + arow) * KK_ + aslx;
  const unsigned short* pWb = Wb + (size_t)(e0 + arow) * KK_ + aslx;
  const int wofs = wave * 1024;                      // wave slice of round (bytes)

  // ds_read per-thread constants (swizzled read side)
  const int rA7 = (wm * 128 + fr) * 128;             // A row byte offset
  const int rB7 = (wn * 64 + fr) * 128;              // B row byte offset
  const int fx = fr & 7;
  const int sk0 = (kg ^ fx) * 16;                    // k-half 0 slot byte
  const int sk1 = sk0 ^ 64;                          // k-half 1 slot byte

  f32x4 acc[8][4];
  #pragma unroll
  for (int i = 0; i < 8; i++)
    #pragma unroll
    for (int j = 0; j < 4; j++)
      acc[i][j] = (f32x4){0.f, 0.f, 0.f, 0.f};
  bf16x8 bfv[4];

  // prologue: stage K-tile 0 into buf0
  STA(0, smem, 0); STA(2, smem, 0); STB(0, smem, 0);
  STB(1, smem, 0); STB(2, smem, 0); STB(3, smem, 0);
  STA(1, smem, 0); STA(3, smem, 0);
  asm volatile("s_waitcnt vmcnt(2)" ::: "memory");
  __builtin_amdgcn_s_barrier();

  #pragma unroll 1
  for (int t = 0; t < 15; ++t) {                     // tiles 0..14, prefetch t+1
    char* cb = smem + ((t & 1) << 16);
    char* nb = smem + (((t + 1) & 1) << 16);
    const int kn = (t + 1) * 64;
    PHASE(cb, 0, 0, {STA(0, nb, kn); STA(2, nb, kn); STB(0, nb, kn);},
          asm volatile("s_waitcnt vmcnt(3)" ::: "memory"));
    PHASE(cb, 1, 0, {STB(1, nb, kn); STB(2, nb, kn); STB(3, nb, kn);}, );
    PHASE(cb, 0, 1, {STA(1, nb, kn); STA(3, nb, kn);}, );
    PHASE(cb, 1, 1, {},
          asm volatile("s_waitcnt vmcnt(2)" ::: "memory"));
  }
  {                                                  // peeled tile 15 (buf1)
    char* cb = smem + 65536;
    PHASE(cb, 0, 0, {}, asm volatile("s_waitcnt vmcnt(0)" ::: "memory"));
    PHASE(cb, 1, 0, {}, );
    PHASE(cb, 0, 1, {}, );
    PHASE(cb, 1, 1, {}, );
  }
  // last PHASE's trailing barrier: all LDS reads done -> smem reusable

  // ===== epilogue: activation + in-register chunk scan + packed ZG ========
  // lane's channel (j = 0,1): d = dw0 + j*16 + fr ; k = acc[a][j], th = acc[a][j+2]
  const int dw0 = (swz & 7) * 128 + wn * 32;         // wave's 32 channels
  const int t0 = m0 & 4095;                          // t base within batch
  const int bidx = m0 >> 12;                         // batch

  float bzv[2], bhv[2];
  #pragma unroll
  for (int j = 0; j < 2; ++j) {
    bzv[j] = bz[dw0 + j * 16 + fr];
    bhv[j] = bh[dw0 + j * 16 + fr];
  }

  unsigned int* ew = (unsigned int*)(smem + wave * 9216);  // [64 t][36 dw]
  const int sub = lane & 7, rowr = lane >> 3;

  #pragma unroll
  for (int p = 0; p < 2; ++p) {                      // two 64-t chunks
    float PP[2] = {1.f, 1.f}, QQ[2] = {0.f, 0.f};
    #pragma unroll
    for (int ii = 0; ii < 4; ++ii) {                 // ascending t blocks of 16
      #pragma unroll
      for (int j = 0; j < 2; ++j) {
        float segP = 1.f, segQ = 0.f;
        #pragma unroll
        for (int r = 0; r < 4; ++r) {                // 4 consecutive t
          float kz = acc[p * 4 + ii][j][r] + bzv[j];
          float th = acc[p * 4 + ii][j + 2][r] + bhv[j];
          float z = 1.0f / (1.0f + __expf(-kz));
          float g = (th >= 0.0f) ? (th + 0.5f)
                                 : (1.0f / (1.0f + __expf(-th)));
          unsigned int pk =
              (unsigned int)__half_as_ushort(__float2half(z)) |
              ((unsigned int)__half_as_ushort(__float2half(g)) << 16);
          ew[(ii * 16 + kg * 4 + r) * 36 + j * 16 + fr] = pk;
          float aa = 1.f - z;
          segP *= aa;
          segQ = fmaf(aa, segQ, z * g);
        }
        // suffix-combine across kg (t-ordered: kg ascending = later)
        float p1 = __shfl_down(segP, 16), q1 = __shfl_down(segQ, 16);
        segQ = fmaf(p1, segQ, q1); segP *= p1;
        float p2 = __shfl_down(segP, 32), q2 = __shfl_down(segQ, 32);
        segQ = fmaf(p2, segQ, q2); segP *= p2;
        // lanes kg==0 now hold the 16-t combine; fold into chunk
        QQ[j] = fmaf(segP, QQ[j], segQ);
        PP[j] *= segP;
      }
    }
    if (kg == 0) {                                   // one lane per (d, chunk)
      const int cg = (t0 >> 6) + wm * 2 + p;
      #pragma unroll
      for (int j = 0; j < 2; ++j) {
        size_t po = ((size_t)bidx * NCH + cg) * DD_ + dw0 + j * 16 + fr;
        Pp[po] = PP[j];
        Qq[po] = QQ[j];
      }
    }
    // coalesced ZG store via LDS readback (wave-synchronous, own region)
    #pragma unroll
    for (int q = 0; q < 8; ++q) {
      int rl = q * 8 + rowr;
      uint4 v = *reinterpret_cast<const uint4*>(&ew[rl * 36 + sub * 4]);
      size_t rg = (size_t)(m0 + wm * 128 + p * 64 + rl);
      *reinterpret_cast<uint4*>(&ZG[rg * DD_ + dw0 + sub * 4]) = v;
    }
  }
}

// ---------------- scan phase B: exclusive scan over chunks ----------------
__global__ __launch_bounds__(256) void scan_combine(
    const float* __restrict__ P, const float* __restrict__ Q,
    float* __restrict__ H) {
  const int d = blockIdx.x * 256 + threadIdx.x;   // gridDim.x = 4 -> d 0..1023
  const int b = blockIdx.y;
  float h = 0.f;
  for (int c = 0; c < NCH; ++c) {
    size_t o = ((size_t)b * NCH + c) * DD_ + d;
    H[o] = h;
    h = fmaf(P[o], h, Q[o]);
  }
}

// ---------------- scan phase C: apply + write output ----------------
__global__ __launch_bounds__(256) void scan_apply(
    const uint4* __restrict__ ZG, const float4* __restrict__ H,
    float4* __restrict__ out) {
  const int d4 = threadIdx.x;
  const int c  = blockIdx.x;
  const int b  = blockIdx.y;
  float4 h = H[((size_t)b * NCH + c) * (DD_ / 4) + d4];
  size_t base = ((size_t)b * TT_ + (size_t)c * LCH) * (DD_ / 4) + d4;
  for (int t = 0; t < LCH; ++t) {
    uint4 w = ZG[base + (size_t)t * (DD_ / 4)];
    float z, g, a;
    z = __half2float(__ushort_as_half((unsigned short)(w.x & 0xffff)));
    g = __half2float(__ushort_as_half((unsigned short)(w.x >> 16)));
    a = 1.f - z; h.x = fmaf(a, h.x, z * g);
    z = __half2float(__ushort_as_half((unsigned short)(w.y & 0xffff)));
    g = __half2float(__ushort_as_half((unsigned short)(w.y >> 16)));
    a = 1.f - z; h.y = fmaf(a, h.y, z * g);
    z = __half2float(__ushort_as_half((unsigned short)(w.z & 0xffff)));
    g = __half2float(__ushort_as_half((unsigned short)(w.z >> 16)));
    a = 1.f - z; h.z = fmaf(a, h.z, z * g);
    z = __half2float(__ushort_as_half((unsigned short)(w.w & 0xffff)));
    g = __half2float(__ushort_as_half((unsigned short)(w.w >> 16)));
    a = 1.f - z; h.w = fmaf(a, h.w, z * g);
    out[base + (size_t)t * (DD_ / 4)] = h;
  }
}

extern "C" void kernel_launch(void* const* d_in, const int* in_sizes, int n_in,
                              void* d_out, int out_size, void* d_ws, size_t ws_size,
                              hipStream_t stream) {
  const float* X  = (const float*)d_in[0];  // [8,4096,1024]
  const float* Wz = (const float*)d_in[1];  // [1024,1024]
  const float* bz = (const float*)d_in[2];
  const float* Wh = (const float*)d_in[3];
  const float* bh = (const float*)d_in[4];
  float* out = (float*)d_out;

  const size_t szXb = (size_t)MM_ * DD_ * 2;      // 64 MiB  bf16 X
  const size_t szWb = (size_t)2 * DD_ * DD_ * 2;  //  4 MiB  bf16 Wcat
  const size_t szZG = (size_t)MM_ * DD_ * 4;      // 128 MiB packed z,g
  const size_t szPQ = (size_t)BB_ * NCH * DD_ * 4;//  2 MiB  each

  char* ws = (char*)d_ws;
  unsigned short *Xb, *Wb;
  const size_t needA = szXb + szWb + szZG + 3 * szPQ;
  if (ws_size >= needA) {
    Xb = (unsigned short*)ws;              ws += szXb;
    Wb = (unsigned short*)ws;              ws += szWb;
  } else {
    // fallback: stage X/W inside d_out (dead until scan_apply), rest in ws
    Xb = (unsigned short*)d_out;
    Wb = (unsigned short*)((char*)d_out + szXb);
  }
  unsigned int* ZG = (unsigned int*)ws;  ws += szZG;
  float* P = (float*)ws;  ws += szPQ;
  float* Q = (float*)ws;  ws += szPQ;
  float* H = (float*)ws;

  // 1) convert inputs to bf16 (X straight; W interleaved into Wcat)
  cvt_f32_bf16<<<2048, 256, 0, stream>>>((const float4*)X, (ushort4*)Xb,
                                         (int)((size_t)MM_ * DD_ / 4));
  cvt_w<<<2048, 256, 0, stream>>>((const float4*)Wz, (const float4*)Wh,
                                  (ushort4*)Wb);
  // 2) fused GEMM -> packed ZG + per-chunk P,Q  (M=32768, N=2048, K=1024)
  gemm_fused<<<(MM_ / 256) * ((2 * DD_) / 256), 512, 131072, stream>>>(
      Xb, Wb, bz, bh, ZG, P, Q);

  // 3) chunk combine + apply
  scan_combine<<<dim3(4, BB_), 256, 0, stream>>>(P, Q, H);
  scan_apply<<<dim3(NCH, BB_), 256, 0, stream>>>((const uint4*)ZG,
                                                 (const float4*)H, (float4*)out);
}